// Round 4
// baseline (2470.742 us; speedup 1.0000x reference)
//
#include <hip/hip_runtime.h>

typedef unsigned short u16;
typedef _Float16 f16x8_t __attribute__((ext_vector_type(8)));
typedef short    i16x8_t __attribute__((ext_vector_type(8)));
typedef short    i16x4_t __attribute__((ext_vector_type(4)));
typedef float    f32x4_t __attribute__((ext_vector_type(4)));

// force a loaded value to stay materialized in VGPRs (no remat/sinking)
#define PIN(x) asm volatile("" : "+v"(x))

// ---- helpers ---------------------------------------------------------------
static __device__ __forceinline__ u16 f2h(float f) {
  _Float16 h = (_Float16)f;  // RNE
  return __builtin_bit_cast(u16, h);
}
static __device__ __forceinline__ f32x4_t mfma16h(i16x8_t a, i16x8_t b, f32x4_t c) {
  return __builtin_amdgcn_mfma_f32_16x16x32_f16(
      __builtin_bit_cast(f16x8_t, a), __builtin_bit_cast(f16x8_t, b), c, 0, 0, 0);
}
static __device__ __forceinline__ float sigmoidf_(float x) { return 1.f / (1.f + __expf(-x)); }
static __device__ __forceinline__ float tanhf_(float x) { return 1.f - 2.f / (__expf(2.f * x) + 1.f); }

// ---- prep: LSTM weights pre-swizzled into MFMA fragment order --------------
// wpack[dir][tau][kb][lane][8]: tau = jb*4+g (jb = j-block, g = gate),
// kb in [0,12), lane = quad*16+mrow. Element e: n = g*256+jb*16+mrow,
// k = kb*32+quad*8+e; value = k<128 ? Wi[k][n] : Wh[k-128][n].
__global__ __launch_bounds__(256) void prep_wpack(const float* __restrict__ Wi_f,
                                                  const float* __restrict__ Wh_f,
                                                  const float* __restrict__ Wi_r,
                                                  const float* __restrict__ Wh_r,
                                                  u16* __restrict__ wpack) {
  int id = blockIdx.x * 256 + threadIdx.x;
  if (id >= 786432) return;  // 2*64*12*64*8
  int e = id & 7, r = id >> 3;
  int lane = r & 63; r >>= 6;
  int kb = r % 12; r /= 12;
  int tau = r & 63, dir = r >> 6;
  int mrow = lane & 15, quad = lane >> 4;
  int jb = tau >> 2, g = tau & 3;
  int n = g * 256 + jb * 16 + mrow;
  int k = kb * 32 + quad * 8 + e;
  const float* Wi = dir ? Wi_r : Wi_f;
  const float* Wh = dir ? Wh_r : Wh_f;
  float v = (k < 128) ? Wi[k * 1024 + n] : Wh[(k - 128) * 1024 + n];
  wpack[id] = f2h(v);
}

// ---- prep: MLP W^T in f16 (W1[512][256], W2[256][256], W3[256][128]) -------
__global__ __launch_bounds__(256) void prep_small(const float* __restrict__ W1,
                                                  const float* __restrict__ W2,
                                                  const float* __restrict__ W3,
                                                  u16* __restrict__ w1t,
                                                  u16* __restrict__ w2t,
                                                  u16* __restrict__ w3t) {
  int id = blockIdx.x * 256 + threadIdx.x;
  if (id < 131072) { int n = id >> 9, k = id & 511; w1t[id] = f2h(W1[k * 256 + n]); return; }
  id -= 131072;
  if (id < 65536) { int n = id >> 8, k = id & 255; w2t[id] = f2h(W2[k * 256 + n]); return; }
  id -= 65536;
  if (id < 32768) { int n = id >> 8, k = id & 255; w3t[id] = f2h(W3[k * 128 + n]); }
}

// ---- bidirectional LSTM v7: v6 + RA budget unlock (waves_per_eu 2,2) -------
// Occupancy is LDS-bound at 1 block/CU = 8 waves = 2 waves/SIMD, so VGPRs up
// to 256/wave are free; amdgpu_waves_per_eu(2,2) tells the RA exactly that
// (v6's PIN at a 128-reg budget spilled to scratch: FETCH +135 MB, dur +450us).
// Per 4-step chunk (P slab 256 KB/block -> 2 MB/XCD, L2-resident):
//   phase G: P[s][tau] = bias + x_t@Wi (kb 0..3), Wi frags PINNED in regs.
//   phase R: 4 recurrence steps; acc = P + h@Wh. Wh: kb 4,5 LDS (128 KB),
//            kb 6..9 PINNED in 128 VGPR/wave, kb 10,11 + P streamed with
//            1-tau-ahead prefetch (all L2-hot).
__global__ __launch_bounds__(512)
__attribute__((amdgpu_waves_per_eu(2, 2))) void lstm_kernel(
    const float* __restrict__ x0, const u16* __restrict__ wpack,
    const float* __restrict__ bi_f, const float* __restrict__ bh_f,
    const float* __restrict__ bi_r, const float* __restrict__ bh_r,
    u16* __restrict__ x1, float* __restrict__ pbuf) {
  __shared__ __align__(16) u16 lwh[64][2][64][8];  // Wh kb 4,5 resident (128 KB)
  __shared__ __align__(16) u16 ah[2][16][264];     // h panel (f16)
  __shared__ __align__(16) u16 xs[2][16][136];     // x staging for phase G (2 t)

  const int tid = threadIdx.x;
  const int lane = tid & 63;
  const int w = tid >> 6;               // wave id 0..7
  const int dir = blockIdx.x >> 5;
  const int b0 = (blockIdx.x & 31) * 16;
  const u16* wpk = wpack + (size_t)dir * (64 * 12 * 64 * 8);
  const float* bi = dir ? bi_r : bi_f;
  const float* bh = dir ? bh_r : bh_f;
  const int mrow = lane & 15, quad = lane >> 4;
  const int jb0 = w << 1;
  float* pblk = pbuf + ((size_t)blockIdx.x << 16);  // 256 KB slab per block

  float bias_[8];
#pragma unroll
  for (int ti = 0; ti < 8; ++ti) {
    int tau = 8 * w + ti;
    int n = (tau & 3) * 256 + (tau >> 2) * 16 + mrow;
    bias_[ti] = bi[n] + bh[n];
  }
  float c_[2][4] = {};

  // LDS-resident Wh slices kb 4,5: 8192 frags of 16 B, 16 per thread
#pragma unroll
  for (int r = 0; r < 16; ++r) {
    int d = r * 512 + tid;                  // frag index: tau*128 + kb*64 + lane
    int ltau = d >> 7, lkb = (d >> 6) & 1, llane = d & 63;
    *(i16x8_t*)&lwh[ltau][lkb][llane][0] =
        *(const i16x8_t*)(wpk + (((size_t)ltau * 12 + 4 + lkb) * 64 + llane) * 8);
  }
  // h_{-1} = 0 (both parities)
  for (int i = tid; i < 2 * 16 * 264; i += 512) ((u16*)ah)[i] = 0;
  __syncthreads();

  i16x8_t wreg[8][4];  // phase G: Wi kb0..3; phase R: Wh kb6..9 (PINNED)

  for (int chunk = 0; chunk < 32; ++chunk) {
    // ================= phase G: P = bias + x@Wi for 4 steps =================
#pragma unroll
    for (int ti = 0; ti < 8; ++ti)
#pragma unroll
      for (int kb = 0; kb < 4; ++kb) {
        wreg[ti][kb] =
            *(const i16x8_t*)(wpk + (((size_t)(8 * w + ti) * 12 + kb) * 64 + lane) * 8);
        PIN(wreg[ti][kb]);
      }

    for (int tp = 0; tp < 2; ++tp) {
      {  // stage 2 timesteps of x into xs (f16)
        int tt0 = tid >> 8;                 // 0..1
        int row = (tid >> 4) & 15;
        int c8 = (tid & 15) * 8;
        int t = chunk * 4 + tp * 2 + tt0;
        int teff = dir ? 127 - t : t;
        const float* xp = x0 + ((size_t)(b0 + row) * 128 + teff) * 128 + c8;
        float4 va = *(const float4*)(xp);
        float4 vb = *(const float4*)(xp + 4);
        i16x8_t xv8;
        xv8[0] = (short)f2h(va.x); xv8[1] = (short)f2h(va.y);
        xv8[2] = (short)f2h(va.z); xv8[3] = (short)f2h(va.w);
        xv8[4] = (short)f2h(vb.x); xv8[5] = (short)f2h(vb.y);
        xv8[6] = (short)f2h(vb.z); xv8[7] = (short)f2h(vb.w);
        *(i16x8_t*)&xs[tt0][row][c8] = xv8;
      }
      __syncthreads();
#pragma unroll
      for (int tt = 0; tt < 2; ++tt) {
        i16x8_t afx[4];
#pragma unroll
        for (int kb = 0; kb < 4; ++kb)
          afx[kb] = *(const i16x8_t*)&xs[tt][mrow][kb * 32 + quad * 8];
        int sloc = tp * 2 + tt;
#pragma unroll
        for (int ti = 0; ti < 8; ++ti) {
          float bv = bias_[ti];
          f32x4_t a = {bv, bv, bv, bv};
          a = mfma16h(afx[0], wreg[ti][0], a);
          a = mfma16h(afx[1], wreg[ti][1], a);
          a = mfma16h(afx[2], wreg[ti][2], a);
          a = mfma16h(afx[3], wreg[ti][3], a);
          *(f32x4_t*)(pblk + (((size_t)sloc * 64 + 8 * w + ti) * 64 + lane) * 4) = a;
        }
      }
      __syncthreads();  // xs reads done before next stage overwrites
    }

    // reload wreg with resident Wh slices kb 6..9 (PINNED for the R loop)
#pragma unroll
    for (int ti = 0; ti < 8; ++ti)
#pragma unroll
      for (int kk = 0; kk < 4; ++kk) {
        wreg[ti][kk] =
            *(const i16x8_t*)(wpk + (((size_t)(8 * w + ti) * 12 + 6 + kk) * 64 + lane) * 8);
        PIN(wreg[ti][kk]);
      }

    // ================= phase R: 4 recurrence steps =========================
    for (int s = 0; s < 4; ++s) {
      const int t = chunk * 4 + s;
      const int par = t & 1;
      __syncthreads();  // orders prev h-writes / G stores vs this step's reads

      // coalesced flush h_{t-1} -> x1 (16 B/thread)
      if (t > 0) {
        int fm = tid >> 5, fj = (tid & 31) * 8;
        i16x8_t hh = *(const i16x8_t*)&ah[par ^ 1][fm][fj];
        *(i16x8_t*)(x1 + ((size_t)((b0 + fm) * 128 + (t - 1))) * 512 + dir * 256 + fj) = hh;
      }

      // h fragments (shared across this wave's 8 taus)
      i16x8_t af[8];
#pragma unroll
      for (int kb = 0; kb < 8; ++kb)
        af[kb] = *(const i16x8_t*)&ah[par ^ 1][mrow][kb * 32 + quad * 8];

      // pipeline: P frag + 2 streamed Wh frags, 1 tau ahead
      f32x4_t pf[2];
      i16x8_t wA[2], wB[2];
      {
        const int tau0 = 8 * w;
        pf[0] = *(const f32x4_t*)(pblk + (((size_t)s * 64 + tau0) * 64 + lane) * 4);
        wA[0] = *(const i16x8_t*)(wpk + (((size_t)tau0 * 12 + 10) * 64 + lane) * 8);
        wB[0] = *(const i16x8_t*)(wpk + (((size_t)tau0 * 12 + 11) * 64 + lane) * 8);
      }
#pragma unroll
      for (int j = 0; j < 2; ++j) {
        f32x4_t acc4[4];
#pragma unroll
        for (int g = 0; g < 4; ++g) {
          const int ti = j * 4 + g, cur = ti & 1, nxt = cur ^ 1;
          if (ti < 7) {
            const int taun = 8 * w + ti + 1;
            pf[nxt] = *(const f32x4_t*)(pblk + (((size_t)s * 64 + taun) * 64 + lane) * 4);
            wA[nxt] = *(const i16x8_t*)(wpk + (((size_t)taun * 12 + 10) * 64 + lane) * 8);
            wB[nxt] = *(const i16x8_t*)(wpk + (((size_t)taun * 12 + 11) * 64 + lane) * 8);
          }
          const int tau = 8 * w + ti;
          f32x4_t a = pf[cur];
          a = mfma16h(af[0], *(const i16x8_t*)&lwh[tau][0][lane][0], a);
          a = mfma16h(af[1], *(const i16x8_t*)&lwh[tau][1][lane][0], a);
          a = mfma16h(af[2], wreg[ti][0], a);
          a = mfma16h(af[3], wreg[ti][1], a);
          a = mfma16h(af[4], wreg[ti][2], a);
          a = mfma16h(af[5], wreg[ti][3], a);
          a = mfma16h(af[6], wA[cur], a);
          a = mfma16h(af[7], wB[cur], a);
          acc4[g] = a;
        }
        // in-register gate update; lane holds (m = quad*4+r, j-col)
        const int jcol = (jb0 + j) * 16 + mrow;
#pragma unroll
        for (int r = 0; r < 4; ++r) {
          float fv = sigmoidf_(acc4[0][r]);
          float iv = sigmoidf_(acc4[1][r]);
          float av = tanhf_(acc4[2][r]);
          float ov = sigmoidf_(acc4[3][r]);
          float cv = fv * c_[j][r] + iv * av;
          c_[j][r] = cv;
          ah[par][(quad << 2) | r][jcol] = f2h(ov * tanhf_(cv));
        }
      }
    }
  }
  // epilogue: flush h_127 (par of t=127 is 1)
  __syncthreads();
  {
    int fm = tid >> 5, fj = (tid & 31) * 8;
    i16x8_t hh = *(const i16x8_t*)&ah[1][fm][fj];
    *(i16x8_t*)(x1 + ((size_t)((b0 + fm) * 128 + 127)) * 512 + dir * 256 + fj) = hh;
  }
}

// ---- fused MLP + heads (unchanged — passing) ------------------------------
__global__ __launch_bounds__(512, 1) void mlp_kernel(
    const u16* __restrict__ x1, const u16* __restrict__ w1t,
    const u16* __restrict__ w2t, const u16* __restrict__ w3t,
    const float* __restrict__ b1, const float* __restrict__ b2,
    const float* __restrict__ b3, float* __restrict__ out) {
  __shared__ __align__(16) u16 X2[128][264];
  __shared__ __align__(16) u16 X3[128][264];
  const int tid = threadIdx.x;
  const int lane = tid & 63, wv = tid >> 6;
  const int mrow = lane & 15, quad = lane >> 4;
  const int r0 = blockIdx.x * 128;
  const f32x4_t zero4 = {0.f, 0.f, 0.f, 0.f};

  // stage 1: X2[128][256] = leaky(x1[128,512] @ W1 + b1)
  {
    f32x4_t acc[16];
#pragma unroll
    for (int n = 0; n < 16; ++n) acc[n] = zero4;
    for (int kb = 0; kb < 16; ++kb) {
      int k = kb * 32 + quad * 8;
      i16x8_t a = *(const i16x8_t*)(x1 + (size_t)(r0 + wv * 16 + mrow) * 512 + k);
#pragma unroll
      for (int n = 0; n < 16; ++n) {
        i16x8_t b = *(const i16x8_t*)(w1t + (n * 16 + mrow) * 512 + k);
        acc[n] = mfma16h(a, b, acc[n]);
      }
    }
#pragma unroll
    for (int n = 0; n < 16; ++n)
#pragma unroll
      for (int r = 0; r < 4; ++r) {
        int m = wv * 16 + quad * 4 + r;
        int col = n * 16 + mrow;
        float v = acc[n][r] + b1[col];
        v = v > 0.f ? v : 0.1f * v;
        X2[m][col] = f2h(v);
      }
  }
  __syncthreads();

  // stage 2: X3[128][256] = leaky(X2 @ W2 + b2), K=256
  {
    f32x4_t acc[16];
#pragma unroll
    for (int n = 0; n < 16; ++n) acc[n] = zero4;
#pragma unroll
    for (int kb = 0; kb < 8; ++kb) {
      int k = kb * 32 + quad * 8;
      i16x8_t a = *(const i16x8_t*)&X2[wv * 16 + mrow][k];
#pragma unroll
      for (int n = 0; n < 16; ++n) {
        i16x8_t b = *(const i16x8_t*)(w2t + (n * 16 + mrow) * 256 + k);
        acc[n] = mfma16h(a, b, acc[n]);
      }
    }
#pragma unroll
    for (int n = 0; n < 16; ++n)
#pragma unroll
      for (int r = 0; r < 4; ++r) {
        int m = wv * 16 + quad * 4 + r;
        int col = n * 16 + mrow;
        float v = acc[n][r] + b2[col];
        v = v > 0.f ? v : 0.1f * v;
        X3[m][col] = f2h(v);
      }
  }
  __syncthreads();

  // stage 3: XF[128][128] = X3 @ W3 + b3 (fp32; overlays dead X2)
  float (*XF)[130] = (float (*)[130]) & X2[0][0];
  {
    f32x4_t acc[8];
#pragma unroll
    for (int n = 0; n < 8; ++n) acc[n] = zero4;
#pragma unroll
    for (int kb = 0; kb < 8; ++kb) {
      int k = kb * 32 + quad * 8;
      i16x8_t a = *(const i16x8_t*)&X3[wv * 16 + mrow][k];
#pragma unroll
      for (int n = 0; n < 8; ++n) {
        i16x8_t b = *(const i16x8_t*)(w3t + (n * 16 + mrow) * 256 + k);
        acc[n] = mfma16h(a, b, acc[n]);
      }
    }
#pragma unroll
    for (int n = 0; n < 8; ++n)
#pragma unroll
      for (int r = 0; r < 4; ++r) {
        int m = wv * 16 + quad * 4 + r;
        int col = n * 16 + mrow;
        XF[m][col] = acc[n][r] + b3[col];
      }
  }
  __syncthreads();

  // heads: cols 0:64 sigmoid; softmax over [64,72), [72,88), [88,128)
  if (tid < 128) {
    int row = tid;
    float* xr = XF[row];
    float* op = out + (size_t)(r0 + row) * 128;
    for (int cc = 0; cc < 64; ++cc) op[cc] = sigmoidf_(xr[cc]);
  } else if (tid < 256) {
    int row = tid - 128;
    float* xr = XF[row];
    float* op = out + (size_t)(r0 + row) * 128;
    const int s0s[3] = {64, 72, 88};
    const int s1s[3] = {72, 88, 128};
    for (int s = 0; s < 3; ++s) {
      int s0 = s0s[s], s1 = s1s[s];
      float mx = xr[s0];
      for (int q = s0 + 1; q < s1; ++q) mx = fmaxf(mx, xr[q]);
      float sum = 0.f;
      for (int q = s0; q < s1; ++q) { float e = __expf(xr[q] - mx); xr[q] = e; sum += e; }
      float inv = 1.f / sum;
      for (int q = s0; q < s1; ++q) op[q] = xr[q] * inv;
    }
  }
}

// ---- launch ----------------------------------------------------------------
extern "C" void kernel_launch(void* const* d_in, const int* in_sizes, int n_in,
                              void* d_out, int out_size, void* d_ws, size_t ws_size,
                              hipStream_t stream) {
  const float* x0   = (const float*)d_in[0];
  const float* Wi_f = (const float*)d_in[1];
  const float* bi_f = (const float*)d_in[2];
  const float* Wh_f = (const float*)d_in[3];
  const float* bh_f = (const float*)d_in[4];
  const float* Wi_r = (const float*)d_in[5];
  const float* bi_r = (const float*)d_in[6];
  const float* Wh_r = (const float*)d_in[7];
  const float* bh_r = (const float*)d_in[8];
  const float* W1 = (const float*)d_in[9];
  const float* b1 = (const float*)d_in[10];
  const float* W2 = (const float*)d_in[11];
  const float* b2 = (const float*)d_in[12];
  const float* W3 = (const float*)d_in[13];
  const float* b3 = (const float*)d_in[14];
  float* out = (float*)d_out;

  char* ws = (char*)d_ws;
  u16* w1t   = (u16*)(ws + 0);         // 262144 B
  u16* w2t   = (u16*)(ws + 262144);    // 131072 B
  u16* w3t   = (u16*)(ws + 393216);    // 65536 B
  u16* wpack = (u16*)(ws + 458752);    // 1572864 B
  u16* x1    = (u16*)(ws + 2031616);   // 67108864 B
  float* pbuf = (float*)(ws + 69140480);  // 16777216 B (64 blocks x 256 KB)

  hipLaunchKernelGGL(prep_wpack, dim3(3072), dim3(256), 0, stream,
                     Wi_f, Wh_f, Wi_r, Wh_r, wpack);
  hipLaunchKernelGGL(prep_small, dim3(896), dim3(256), 0, stream,
                     W1, W2, W3, w1t, w2t, w3t);
  hipLaunchKernelGGL(lstm_kernel, dim3(64), dim3(512), 0, stream,
                     x0, wpack, bi_f, bh_f, bi_r, bh_r, x1, pbuf);
  hipLaunchKernelGGL(mlp_kernel, dim3(512), dim3(512), 0, stream,
                     x1, w1t, w2t, w3t, b1, b2, b3, out);
}

// Round 5
// 1163.815 us; speedup vs baseline: 2.1230x; 2.1230x over previous
//
#include <hip/hip_runtime.h>

typedef unsigned short u16;
typedef _Float16 f16x8_t __attribute__((ext_vector_type(8)));
typedef short    i16x8_t __attribute__((ext_vector_type(8)));
typedef short    i16x4_t __attribute__((ext_vector_type(4)));
typedef float    f32x4_t __attribute__((ext_vector_type(4)));

// force a loaded value to stay materialized in VGPRs (no remat/sinking)
#define PIN(x) asm volatile("" : "+v"(x))

// ---- helpers ---------------------------------------------------------------
static __device__ __forceinline__ u16 f2h(float f) {
  _Float16 h = (_Float16)f;  // RNE
  return __builtin_bit_cast(u16, h);
}
static __device__ __forceinline__ f32x4_t mfma16h(i16x8_t a, i16x8_t b, f32x4_t c) {
  return __builtin_amdgcn_mfma_f32_16x16x32_f16(
      __builtin_bit_cast(f16x8_t, a), __builtin_bit_cast(f16x8_t, b), c, 0, 0, 0);
}
static __device__ __forceinline__ float sigmoidf_(float x) { return 1.f / (1.f + __expf(-x)); }
static __device__ __forceinline__ float tanhf_(float x) { return 1.f - 2.f / (__expf(2.f * x) + 1.f); }

// ---- prep: LSTM weights pre-swizzled into MFMA fragment order --------------
// wpack[dir][tau][kb][lane][8]: tau = jb*4+g (jb = j-block, g = gate),
// kb in [0,12), lane = quad*16+mrow. Element e: n = g*256+jb*16+mrow,
// k = kb*32+quad*8+e; value = k<128 ? Wi[k][n] : Wh[k-128][n].
__global__ __launch_bounds__(256) void prep_wpack(const float* __restrict__ Wi_f,
                                                  const float* __restrict__ Wh_f,
                                                  const float* __restrict__ Wi_r,
                                                  const float* __restrict__ Wh_r,
                                                  u16* __restrict__ wpack) {
  int id = blockIdx.x * 256 + threadIdx.x;
  if (id >= 786432) return;  // 2*64*12*64*8
  int e = id & 7, r = id >> 3;
  int lane = r & 63; r >>= 6;
  int kb = r % 12; r /= 12;
  int tau = r & 63, dir = r >> 6;
  int mrow = lane & 15, quad = lane >> 4;
  int jb = tau >> 2, g = tau & 3;
  int n = g * 256 + jb * 16 + mrow;
  int k = kb * 32 + quad * 8 + e;
  const float* Wi = dir ? Wi_r : Wi_f;
  const float* Wh = dir ? Wh_r : Wh_f;
  float v = (k < 128) ? Wi[k * 1024 + n] : Wh[(k - 128) * 1024 + n];
  wpack[id] = f2h(v);
}

// ---- prep: MLP W^T in f16 + flag zeroing ----------------------------------
__global__ __launch_bounds__(256) void prep_small(const float* __restrict__ W1,
                                                  const float* __restrict__ W2,
                                                  const float* __restrict__ W3,
                                                  u16* __restrict__ w1t,
                                                  u16* __restrict__ w2t,
                                                  u16* __restrict__ w3t,
                                                  unsigned* __restrict__ flags) {
  int id = blockIdx.x * 256 + threadIdx.x;
  if (id < 8192) flags[id] = 0u;  // sync flags for lstm (re-zeroed every launch)
  if (id < 131072) { int n = id >> 9, k = id & 511; w1t[id] = f2h(W1[k * 256 + n]); return; }
  id -= 131072;
  if (id < 65536) { int n = id >> 8, k = id & 255; w2t[id] = f2h(W2[k * 256 + n]); return; }
  id -= 65536;
  if (id < 32768) { int n = id >> 8, k = id & 255; w3t[id] = f2h(W3[k * 128 + n]); }
}

// ---- bidirectional LSTM v8: 4-way hidden-split, all weights resident -------
// 256 blocks = q(4 gate-slices) x dir(2) x grp(32 batch-groups of 16 rows),
// bid = q*64 + dir*32 + grp (siblings differ by 64 -> same XCD under %8
// round-robin; correctness carried by release/acquire fences regardless).
// Block owns gate-cols tau_g in [16q,16q+16) (N=256): Wh slice (128 KB) fully
// LDS-resident, Wi slice in 32 VGPR/wave -> ZERO per-step weight streaming.
// Per step: stage x_t + h_{t-1} (from x1), 24 MFMA/wave (bias->Wi kb0..3->
// Wh kb4..11, v4-identical order), gate nonlinearity, write h slice to x1,
// publish flag[t]; siblings spin flag==4 before consuming h_t.
// Cooperative launch guarantees 256-block co-residency (1 block/CU).
__global__ __launch_bounds__(512, 2) void lstm_kernel(
    const float* __restrict__ x0, const u16* __restrict__ wpack,
    const float* __restrict__ bi_f, const float* __restrict__ bh_f,
    const float* __restrict__ bi_r, const float* __restrict__ bh_r,
    u16* __restrict__ x1, unsigned* __restrict__ flags) {
  __shared__ __align__(16) u16 lwh[16][8][64][8];  // 128 KB Wh kb4..11, 16 taus
  __shared__ __align__(16) u16 ah[16][264];        // h_{t-1} panel (f16)
  __shared__ __align__(16) u16 xs[16][136];        // x_t panel (f16)
  __shared__ __align__(16) float gbuf[16][257];    // gate pre-activations (f32)

  const int tid = threadIdx.x;
  const int lane = tid & 63;
  const int w = tid >> 6;             // wave 0..7
  const int bid = blockIdx.x;
  const int q = bid >> 6;             // gate-slice 0..3
  const int rem = bid & 63;
  const int dir = rem >> 5;
  const int grp = rem & 31;
  const int b0 = grp * 16;
  const u16* wpk = wpack + (size_t)dir * (64 * 12 * 64 * 8);
  const float* bi = dir ? bi_r : bi_f;
  const float* bh = dir ? bh_r : bh_f;
  const int mrow = lane & 15, quad = lane >> 4;
  const int tauL0 = 2 * w;            // this wave's 2 local n-tiles
  unsigned* flg = flags + (size_t)(dir * 32 + grp) * 128;

  // biases for the wave's 2 taus
  float bias2[2];
#pragma unroll
  for (int lt = 0; lt < 2; ++lt) {
    int tau_g = 16 * q + tauL0 + lt;
    int n = (tau_g & 3) * 256 + (tau_g >> 2) * 16 + mrow;
    bias2[lt] = bi[n] + bh[n];
  }

  // Wh kb4..11 for the block's 16 taus -> LDS (8192 frags of 16 B)
#pragma unroll
  for (int r = 0; r < 16; ++r) {
    int d = r * 512 + tid;
    int ltau = d >> 9, lkb = (d >> 6) & 7, ll = d & 63;
    *(i16x8_t*)&lwh[ltau][lkb][ll][0] =
        *(const i16x8_t*)(wpk + (((size_t)(16 * q + ltau) * 12 + 4 + lkb) * 64 + ll) * 8);
  }
  // Wi kb0..3 for the wave's 2 taus -> registers (32 VGPR), pinned
  i16x8_t wir[2][4];
#pragma unroll
  for (int lt = 0; lt < 2; ++lt)
#pragma unroll
    for (int kb = 0; kb < 4; ++kb) {
      wir[lt][kb] =
          *(const i16x8_t*)(wpk + (((size_t)(16 * q + tauL0 + lt) * 12 + kb) * 64 + lane) * 8);
      PIN(wir[lt][kb]);
    }
  // h_{-1} = 0
  for (int i = tid; i < 16 * 264; i += 512) ((u16*)ah)[i] = 0;

  // c-state: thread owns 2 adjacent cells (row = tid>>5, jj = 2*(tid&31)+e)
  const int crow = tid >> 5;
  const int cj0 = (tid & 31) * 2;
  float c0 = 0.f, c1 = 0.f;
  const int xrow = tid >> 5, xc4 = (tid & 31) * 4;

  for (int t = 0; t < 128; ++t) {
    // issue x_t load early (x0 immutable -> safe to read pre-acquire)
    int teff = dir ? 127 - t : t;
    float4 xv = *(const float4*)(x0 + ((size_t)(b0 + xrow) * 128 + teff) * 128 + xc4);

    if (t > 0 && tid == 0) {
      unsigned iter = 0;
      while (__hip_atomic_load(&flg[t - 1], __ATOMIC_RELAXED, __HIP_MEMORY_SCOPE_AGENT) < 4u) {
        __builtin_amdgcn_s_sleep(8);
        if (++iter > (4u << 20)) break;  // fail-safe: deadlock -> wrong answer, not hang
      }
      (void)__hip_atomic_load(&flg[t - 1], __ATOMIC_ACQUIRE, __HIP_MEMORY_SCOPE_AGENT);
    }
    __syncthreads();  // (1) flag seen by all; prev gbuf reads done

    if (t > 0) {  // stage full h_{t-1} (all 4 slices) from x1: 16 B/thread
      int fm = tid >> 5, fj = (tid & 31) * 8;
      i16x8_t hh = *(const i16x8_t*)(x1 + ((size_t)((b0 + fm) * 128 + (t - 1))) * 512 +
                                     dir * 256 + fj);
      *(i16x8_t*)&ah[fm][fj] = hh;
    }
    {
      i16x4_t x4;
      x4[0] = (short)f2h(xv.x); x4[1] = (short)f2h(xv.y);
      x4[2] = (short)f2h(xv.z); x4[3] = (short)f2h(xv.w);
      *(i16x4_t*)&xs[xrow][xc4] = x4;
    }
    __syncthreads();  // (2) panels ready

    // MFMA phase: 24 MFMA/wave, all operands LDS/reg-resident
    i16x8_t af[12];
#pragma unroll
    for (int kb = 0; kb < 4; ++kb)
      af[kb] = *(const i16x8_t*)&xs[mrow][kb * 32 + quad * 8];
#pragma unroll
    for (int kb = 0; kb < 8; ++kb)
      af[4 + kb] = *(const i16x8_t*)&ah[mrow][kb * 32 + quad * 8];
#pragma unroll
    for (int lt = 0; lt < 2; ++lt) {
      float bv = bias2[lt];
      f32x4_t a = {bv, bv, bv, bv};
      a = mfma16h(af[0], wir[lt][0], a);
      a = mfma16h(af[1], wir[lt][1], a);
      a = mfma16h(af[2], wir[lt][2], a);
      a = mfma16h(af[3], wir[lt][3], a);
#pragma unroll
      for (int kb = 0; kb < 8; ++kb)
        a = mfma16h(af[4 + kb], *(const i16x8_t*)&lwh[tauL0 + lt][kb][lane][0], a);
      int col = (tauL0 + lt) * 16 + mrow;
#pragma unroll
      for (int r = 0; r < 4; ++r) gbuf[quad * 4 + r][col] = a[r];
    }
    __syncthreads();  // (3) gbuf ready

    // gate phase: 2 cells/thread; col(g) = jb_l*64 + g*16 + mr
    {
      float hv[2];
#pragma unroll
      for (int e = 0; e < 2; ++e) {
        int jj = cj0 + e;
        int base = (jj >> 4) * 64 + (jj & 15);
        float fg = gbuf[crow][base];
        float ig = gbuf[crow][base + 16];
        float ag = gbuf[crow][base + 32];
        float og = gbuf[crow][base + 48];
        float cc = e ? c1 : c0;
        float cv = sigmoidf_(fg) * cc + sigmoidf_(ig) * tanhf_(ag);
        if (e) c1 = cv; else c0 = cv;
        hv[e] = sigmoidf_(og) * tanhf_(cv);
      }
      unsigned pack = (unsigned)f2h(hv[0]) | ((unsigned)f2h(hv[1]) << 16);
      *(unsigned*)(x1 + ((size_t)((b0 + crow) * 128 + t)) * 512 + dir * 256 + 64 * q + cj0) =
          pack;
    }
    __syncthreads();  // (4) all h stores drained (barrier implies vmcnt(0))
    if (tid == 0 && t < 127)
      __hip_atomic_fetch_add(&flg[t], 1u, __ATOMIC_RELEASE, __HIP_MEMORY_SCOPE_AGENT);
  }
}

// ---- fused MLP + heads (unchanged — passing) ------------------------------
__global__ __launch_bounds__(512, 1) void mlp_kernel(
    const u16* __restrict__ x1, const u16* __restrict__ w1t,
    const u16* __restrict__ w2t, const u16* __restrict__ w3t,
    const float* __restrict__ b1, const float* __restrict__ b2,
    const float* __restrict__ b3, float* __restrict__ out) {
  __shared__ __align__(16) u16 X2[128][264];
  __shared__ __align__(16) u16 X3[128][264];
  const int tid = threadIdx.x;
  const int lane = tid & 63, wv = tid >> 6;
  const int mrow = lane & 15, quad = lane >> 4;
  const int r0 = blockIdx.x * 128;
  const f32x4_t zero4 = {0.f, 0.f, 0.f, 0.f};

  // stage 1: X2[128][256] = leaky(x1[128,512] @ W1 + b1)
  {
    f32x4_t acc[16];
#pragma unroll
    for (int n = 0; n < 16; ++n) acc[n] = zero4;
    for (int kb = 0; kb < 16; ++kb) {
      int k = kb * 32 + quad * 8;
      i16x8_t a = *(const i16x8_t*)(x1 + (size_t)(r0 + wv * 16 + mrow) * 512 + k);
#pragma unroll
      for (int n = 0; n < 16; ++n) {
        i16x8_t b = *(const i16x8_t*)(w1t + (n * 16 + mrow) * 512 + k);
        acc[n] = mfma16h(a, b, acc[n]);
      }
    }
#pragma unroll
    for (int n = 0; n < 16; ++n)
#pragma unroll
      for (int r = 0; r < 4; ++r) {
        int m = wv * 16 + quad * 4 + r;
        int col = n * 16 + mrow;
        float v = acc[n][r] + b1[col];
        v = v > 0.f ? v : 0.1f * v;
        X2[m][col] = f2h(v);
      }
  }
  __syncthreads();

  // stage 2: X3[128][256] = leaky(X2 @ W2 + b2), K=256
  {
    f32x4_t acc[16];
#pragma unroll
    for (int n = 0; n < 16; ++n) acc[n] = zero4;
#pragma unroll
    for (int kb = 0; kb < 8; ++kb) {
      int k = kb * 32 + quad * 8;
      i16x8_t a = *(const i16x8_t*)&X2[wv * 16 + mrow][k];
#pragma unroll
      for (int n = 0; n < 16; ++n) {
        i16x8_t b = *(const i16x8_t*)(w2t + (n * 16 + mrow) * 256 + k);
        acc[n] = mfma16h(a, b, acc[n]);
      }
    }
#pragma unroll
    for (int n = 0; n < 16; ++n)
#pragma unroll
      for (int r = 0; r < 4; ++r) {
        int m = wv * 16 + quad * 4 + r;
        int col = n * 16 + mrow;
        float v = acc[n][r] + b2[col];
        v = v > 0.f ? v : 0.1f * v;
        X3[m][col] = f2h(v);
      }
  }
  __syncthreads();

  // stage 3: XF[128][128] = X3 @ W3 + b3 (fp32; overlays dead X2)
  float (*XF)[130] = (float (*)[130]) & X2[0][0];
  {
    f32x4_t acc[8];
#pragma unroll
    for (int n = 0; n < 8; ++n) acc[n] = zero4;
#pragma unroll
    for (int kb = 0; kb < 8; ++kb) {
      int k = kb * 32 + quad * 8;
      i16x8_t a = *(const i16x8_t*)&X3[wv * 16 + mrow][k];
#pragma unroll
      for (int n = 0; n < 8; ++n) {
        i16x8_t b = *(const i16x8_t*)(w3t + (n * 16 + mrow) * 256 + k);
        acc[n] = mfma16h(a, b, acc[n]);
      }
    }
#pragma unroll
    for (int n = 0; n < 8; ++n)
#pragma unroll
      for (int r = 0; r < 4; ++r) {
        int m = wv * 16 + quad * 4 + r;
        int col = n * 16 + mrow;
        XF[m][col] = acc[n][r] + b3[col];
      }
  }
  __syncthreads();

  // heads: cols 0:64 sigmoid; softmax over [64,72), [72,88), [88,128)
  if (tid < 128) {
    int row = tid;
    float* xr = XF[row];
    float* op = out + (size_t)(r0 + row) * 128;
    for (int cc = 0; cc < 64; ++cc) op[cc] = sigmoidf_(xr[cc]);
  } else if (tid < 256) {
    int row = tid - 128;
    float* xr = XF[row];
    float* op = out + (size_t)(r0 + row) * 128;
    const int s0s[3] = {64, 72, 88};
    const int s1s[3] = {72, 88, 128};
    for (int s = 0; s < 3; ++s) {
      int s0 = s0s[s], s1 = s1s[s];
      float mx = xr[s0];
      for (int q = s0 + 1; q < s1; ++q) mx = fmaxf(mx, xr[q]);
      float sum = 0.f;
      for (int q = s0; q < s1; ++q) { float e = __expf(xr[q] - mx); xr[q] = e; sum += e; }
      float inv = 1.f / sum;
      for (int q = s0; q < s1; ++q) op[q] = xr[q] * inv;
    }
  }
}

// ---- launch ----------------------------------------------------------------
extern "C" void kernel_launch(void* const* d_in, const int* in_sizes, int n_in,
                              void* d_out, int out_size, void* d_ws, size_t ws_size,
                              hipStream_t stream) {
  const float* x0   = (const float*)d_in[0];
  const float* Wi_f = (const float*)d_in[1];
  const float* bi_f = (const float*)d_in[2];
  const float* Wh_f = (const float*)d_in[3];
  const float* bh_f = (const float*)d_in[4];
  const float* Wi_r = (const float*)d_in[5];
  const float* bi_r = (const float*)d_in[6];
  const float* Wh_r = (const float*)d_in[7];
  const float* bh_r = (const float*)d_in[8];
  const float* W1 = (const float*)d_in[9];
  const float* b1 = (const float*)d_in[10];
  const float* W2 = (const float*)d_in[11];
  const float* b2 = (const float*)d_in[12];
  const float* W3 = (const float*)d_in[13];
  const float* b3 = (const float*)d_in[14];
  float* out = (float*)d_out;

  char* ws = (char*)d_ws;
  u16* w1t   = (u16*)(ws + 0);         // 262144 B
  u16* w2t   = (u16*)(ws + 262144);    // 131072 B
  u16* w3t   = (u16*)(ws + 393216);    // 65536 B
  u16* wpack = (u16*)(ws + 458752);    // 1572864 B
  u16* x1    = (u16*)(ws + 2031616);   // 67108864 B
  unsigned* flags = (unsigned*)(ws + 69140480);  // 32768 B

  hipLaunchKernelGGL(prep_wpack, dim3(3072), dim3(256), 0, stream,
                     Wi_f, Wh_f, Wi_r, Wh_r, wpack);
  hipLaunchKernelGGL(prep_small, dim3(896), dim3(256), 0, stream,
                     W1, W2, W3, w1t, w2t, w3t, flags);
  {
    void* params[8];
    params[0] = (void*)&x0;
    params[1] = (void*)&wpack;
    params[2] = (void*)&bi_f;
    params[3] = (void*)&bh_f;
    params[4] = (void*)&bi_r;
    params[5] = (void*)&bh_r;
    params[6] = (void*)&x1;
    params[7] = (void*)&flags;
    hipLaunchCooperativeKernel((const void*)lstm_kernel, dim3(256), dim3(512),
                               params, 0, stream);
  }
  hipLaunchKernelGGL(mlp_kernel, dim3(512), dim3(512), 0, stream,
                     x1, w1t, w2t, w3t, b1, b2, b3, out);
}